// Round 1
// baseline (491.649 us; speedup 1.0000x reference)
//
#include <hip/hip_runtime.h>
#include <hip/hip_bf16.h>
#include <cstdint>
#include <cstddef>

#define NN 4096
#define FD 256
#define WPR 64  // 64-bit words per adjacency row (4096 bits)

typedef __attribute__((ext_vector_type(8))) unsigned short ushort8v;
typedef __attribute__((ext_vector_type(8))) short short8;
typedef __attribute__((ext_vector_type(4))) float float4v;

static __device__ __forceinline__ unsigned short f2bf(float x) {
    union { float f; unsigned int u; } v; v.f = x;
    unsigned int r = v.u + 0x7FFFu + ((v.u >> 16) & 1u);
    return (unsigned short)(r >> 16);
}

static __device__ __forceinline__ short8 as_s8(ushort8v v) {
    union { ushort8v u; short8 s; } x; x.u = v; return x.s;
}

// ---------------- pack adjacency into bitmask ----------------
__global__ __launch_bounds__(256) void pack_adj(const int* __restrict__ adj,
                                                unsigned long long* __restrict__ bits) {
    const int row = blockIdx.x;
    const int t = threadIdx.x;
    const int wave = t >> 6, lane = t & 63;
    const int* arow = adj + (size_t)row * NN;
    #pragma unroll
    for (int it = 0; it < NN / 256; ++it) {
        int j = it * 256 + wave * 64 + lane;
        unsigned long long m = __ballot(arow[j] > 0);
        if (lane == 0) bits[(size_t)row * WPR + (it * 4 + wave)] = m;
    }
}

// ---------------- convert 4 weight mats to bf16, transposed [n][k] ----------------
__global__ __launch_bounds__(256) void cvt_w(const float* __restrict__ W0, const float* __restrict__ W1,
                                             const float* __restrict__ W2, const float* __restrict__ W3,
                                             unsigned short* __restrict__ Wbt) {
    int idx = blockIdx.x * 256 + threadIdx.x;       // 0 .. 4*65536
    int mat = idx >> 16;
    int within = idx & 65535;
    int n = within >> 8, k = within & 255;
    const float* W = (mat == 0) ? W0 : (mat == 1) ? W1 : (mat == 2) ? W2 : W3;
    Wbt[idx] = f2bf(W[k * 256 + n]);                // Wbt[mat][n][k] = W[k][n]
}

// ---------------- convert input fp32 -> bf16 row-major ----------------
__global__ __launch_bounds__(256) void cvt_h(const float* __restrict__ x, unsigned short* __restrict__ hb) {
    int idx = blockIdx.x * 256 + threadIdx.x;
    hb[idx] = f2bf(x[idx]);
}

// ---------------- projection GEMM: C[M=4096][256] = A(bf16[M][256]) @ B (Wbt [256 n][256 k]) ----------------
__global__ __launch_bounds__(256) void proj_gemm(const unsigned short* __restrict__ A,
                                                 const unsigned short* __restrict__ Bt,
                                                 float* __restrict__ Cf,          // fp32 row-major or null
                                                 unsigned short* __restrict__ Cbt, // bf16 transposed [n][4096] or null
                                                 unsigned short* __restrict__ Crow) { // bf16 row-major or null
    const int t = threadIdx.x;
    const int bm = blockIdx.x >> 2, bn = blockIdx.x & 3;
    const int m0 = bm * 64, n0 = bn * 64;
    __shared__ unsigned short As[64 * 40];
    __shared__ unsigned short Bs[64 * 40];
    const int lane = t & 63, wave = t >> 6;
    const int wm = (wave >> 1) * 32, wn = (wave & 1) * 32;
    const int sr = t >> 2, sc = (t & 3) * 8;
    float4v acc[2][2] = {{{0.f,0.f,0.f,0.f},{0.f,0.f,0.f,0.f}},{{0.f,0.f,0.f,0.f},{0.f,0.f,0.f,0.f}}};

    for (int kk = 0; kk < 256; kk += 32) {
        ushort8v av = *(const ushort8v*)&A[(size_t)(m0 + sr) * 256 + kk + sc];
        ushort8v bv = *(const ushort8v*)&Bt[(size_t)(n0 + sr) * 256 + kk + sc];
        *(ushort8v*)&As[sr * 40 + sc] = av;
        *(ushort8v*)&Bs[sr * 40 + sc] = bv;
        __syncthreads();
        const int kc = (lane >> 4) * 8;
        #pragma unroll
        for (int fm = 0; fm < 2; ++fm) {
            short8 a = as_s8(*(const ushort8v*)&As[(wm + fm * 16 + (lane & 15)) * 40 + kc]);
            #pragma unroll
            for (int fn = 0; fn < 2; ++fn) {
                short8 b = as_s8(*(const ushort8v*)&Bs[(wn + fn * 16 + (lane & 15)) * 40 + kc]);
                acc[fm][fn] = __builtin_amdgcn_mfma_f32_16x16x32_bf16(a, b, acc[fm][fn], 0, 0, 0);
            }
        }
        __syncthreads();
    }

    const int rb = wm + (lane >> 4) * 4;
    const int cb = wn + (lane & 15);
    #pragma unroll
    for (int fm = 0; fm < 2; ++fm)
        #pragma unroll
        for (int fn = 0; fn < 2; ++fn)
            #pragma unroll
            for (int r = 0; r < 4; ++r) {
                int gr = m0 + rb + fm * 16 + r;
                int gc = n0 + cb + fn * 16;
                float v = acc[fm][fn][r];
                if (Cf)  Cf[(size_t)gr * 256 + gc] = v;
                unsigned short bvv = f2bf(v);
                if (Cbt)  Cbt[(size_t)gc * 4096 + gr] = bvv;
                if (Crow) Crow[(size_t)gr * 256 + gc] = bvv;
            }
}

// ---------------- f1/f2: per-row dots of Wh (fp32) with attention vector halves ----------------
__global__ __launch_bounds__(256) void fvec(const float* __restrict__ Wh, const float* __restrict__ a,
                                            float* __restrict__ f1, float* __restrict__ f2) {
    const int wave = threadIdx.x >> 6, lane = threadIdx.x & 63;
    const int i = blockIdx.x * 4 + wave;
    const float* row = Wh + (size_t)i * 256;
    float s1 = 0.f, s2 = 0.f;
    #pragma unroll
    for (int c0 = 0; c0 < 256; c0 += 64) {
        int c = c0 + lane;
        float w = row[c];
        s1 += w * a[c];
        s2 += w * a[256 + c];
    }
    #pragma unroll
    for (int off = 32; off > 0; off >>= 1) {
        s1 += __shfl_down(s1, off, 64);
        s2 += __shfl_down(s2, off, 64);
    }
    if (lane == 0) { f1[i] = s1; f2[i] = s2; }
}

// ---------------- per-row masked softmax stats (online) ----------------
__global__ __launch_bounds__(256) void stats(const unsigned long long* __restrict__ bits,
                                             const float* __restrict__ f1, const float* __restrict__ f2,
                                             float* __restrict__ rowmax, float* __restrict__ invsum) {
    const int i = blockIdx.x;
    const int t = threadIdx.x;
    __shared__ unsigned long long wbits[WPR];
    __shared__ float red_m[256], red_s[256];
    if (t < WPR) wbits[t] = bits[(size_t)i * WPR + t];
    __syncthreads();
    const float f1i = f1[i];
    float m = -3.0e38f, s = 0.f;
    #pragma unroll
    for (int it = 0; it < 16; ++it) {
        int j = it * 256 + t;
        if ((wbits[j >> 6] >> (j & 63)) & 1ULL) {
            float e = f1i + f2[j];
            e = e > 0.f ? e : 0.01f * e;
            if (e > m) { s = s * __expf(m - e) + 1.f; m = e; }
            else       { s += __expf(e - m); }
        }
    }
    red_m[t] = m; red_s[t] = s;
    __syncthreads();
    for (int off = 128; off > 0; off >>= 1) {
        if (t < off) {
            float m2 = red_m[t + off], s2 = red_s[t + off];
            float mo = red_m[t], so = red_s[t];
            float mn = fmaxf(mo, m2);
            red_s[t] = so * __expf(mo - mn) + s2 * __expf(m2 - mn);
            red_m[t] = mn;
        }
        __syncthreads();
    }
    if (t == 0) { rowmax[i] = red_m[0]; invsum[i] = 1.0f / red_s[0]; }
}

// ---------------- attention GEMM: h' = elu( softmax(mask(e)) @ Wh ) ----------------
__global__ __launch_bounds__(256) void att_gemm(const unsigned long long* __restrict__ bits,
                                                const float* __restrict__ f1, const float* __restrict__ f2,
                                                const float* __restrict__ rowmax, const float* __restrict__ invsum,
                                                const unsigned short* __restrict__ Bt,   // Whbt [256 n][4096 k]
                                                float* __restrict__ outf,                 // fp32 out or null
                                                unsigned short* __restrict__ hrow) {      // bf16 row-major out
    const int t = threadIdx.x;
    const int bm = blockIdx.x >> 2, bn = blockIdx.x & 3;
    const int m0 = bm * 64, n0 = bn * 64;
    __shared__ unsigned short As[64 * 40];
    __shared__ unsigned short Bs[64 * 40];
    const int lane = t & 63, wave = t >> 6;
    const int wm = (wave >> 1) * 32, wn = (wave & 1) * 32;
    const int sr = t >> 2, sc = (t & 3) * 8;
    const float f1r = f1[m0 + sr];
    const float mr = rowmax[m0 + sr];
    float4v acc[2][2] = {{{0.f,0.f,0.f,0.f},{0.f,0.f,0.f,0.f}},{{0.f,0.f,0.f,0.f},{0.f,0.f,0.f,0.f}}};

    for (int kk = 0; kk < NN; kk += 32) {
        // generate A tile (softmax numerator weights) on the fly
        unsigned long long w = bits[(size_t)(m0 + sr) * WPR + (kk >> 6)];
        const int sb = (kk & 63) + sc;
        float4v fa = *(const float4v*)&f2[kk + sc];
        float4v fb = *(const float4v*)&f2[kk + sc + 4];
        ushort8v pa;
        #pragma unroll
        for (int jj = 0; jj < 8; ++jj) {
            float e = f1r + ((jj < 4) ? fa[jj] : fb[jj - 4]);
            e = e > 0.f ? e : 0.01f * e;
            float p = ((w >> (sb + jj)) & 1ULL) ? __expf(e - mr) : 0.f;
            pa[jj] = f2bf(p);
        }
        *(ushort8v*)&As[sr * 40 + sc] = pa;
        // stage B tile
        *(ushort8v*)&Bs[sr * 40 + sc] = *(const ushort8v*)&Bt[(size_t)(n0 + sr) * 4096 + kk + sc];
        __syncthreads();
        const int kc = (lane >> 4) * 8;
        #pragma unroll
        for (int fm = 0; fm < 2; ++fm) {
            short8 a = as_s8(*(const ushort8v*)&As[(wm + fm * 16 + (lane & 15)) * 40 + kc]);
            #pragma unroll
            for (int fn = 0; fn < 2; ++fn) {
                short8 b = as_s8(*(const ushort8v*)&Bs[(wn + fn * 16 + (lane & 15)) * 40 + kc]);
                acc[fm][fn] = __builtin_amdgcn_mfma_f32_16x16x32_bf16(a, b, acc[fm][fn], 0, 0, 0);
            }
        }
        __syncthreads();
    }

    const int rb = wm + (lane >> 4) * 4;
    const int cb = wn + (lane & 15);
    #pragma unroll
    for (int fm = 0; fm < 2; ++fm)
        #pragma unroll
        for (int fn = 0; fn < 2; ++fn)
            #pragma unroll
            for (int r = 0; r < 4; ++r) {
                int gr = m0 + rb + fm * 16 + r;
                int gc = n0 + cb + fn * 16;
                float v = acc[fm][fn][r] * invsum[gr];
                v = v > 0.f ? v : (__expf(v) - 1.f);   // ELU
                if (outf) outf[(size_t)gr * 256 + gc] = v;
                hrow[(size_t)gr * 256 + gc] = f2bf(v);
            }
}

extern "C" void kernel_launch(void* const* d_in, const int* in_sizes, int n_in,
                              void* d_out, int out_size, void* d_ws, size_t ws_size,
                              hipStream_t stream) {
    const float* input = (const float*)d_in[0];
    const int*   adj   = (const int*)d_in[1];
    const float* W0    = (const float*)d_in[2];
    const float* W1    = (const float*)d_in[3];
    const float* a1    = (const float*)d_in[4];
    const float* W2    = (const float*)d_in[5];
    const float* a2    = (const float*)d_in[6];
    const float* W3    = (const float*)d_in[7];
    const float* a3    = (const float*)d_in[8];
    float* out = (float*)d_out;
    char* ws = (char*)d_ws;

    unsigned long long* bits = (unsigned long long*)(ws);                 // 2 MB
    unsigned short* h0   = (unsigned short*)(ws + (2u << 20));            // 2 MB bf16 [4096][256]
    unsigned short* h1   = (unsigned short*)(ws + (4u << 20));            // 2 MB
    unsigned short* Whbt = (unsigned short*)(ws + (6u << 20));            // 2 MB bf16 [256][4096]
    float*          Whf  = (float*)(ws + (8u << 20));                     // 4 MB fp32 [4096][256]
    unsigned short* Wbt  = (unsigned short*)(ws + (12u << 20));           // 512 KB (4 mats)
    float* f1v   = (float*)(ws + (12u << 20) + (512u << 10));
    float* f2v   = f1v + 4096;
    float* rmax  = f2v + 4096;
    float* isum  = rmax + 4096;

    pack_adj<<<4096, 256, 0, stream>>>(adj, bits);
    cvt_w<<<1024, 256, 0, stream>>>(W0, W1, W2, W3, Wbt);
    cvt_h<<<4096, 256, 0, stream>>>(input, h0);

    // h = input @ W0  -> h1 (bf16 row-major only)
    proj_gemm<<<256, 256, 0, stream>>>(h0, Wbt + 0 * 65536, nullptr, nullptr, h1);

    // layer 1: A=h1
    proj_gemm<<<256, 256, 0, stream>>>(h1, Wbt + 1 * 65536, Whf, Whbt, nullptr);
    fvec<<<1024, 256, 0, stream>>>(Whf, a1, f1v, f2v);
    stats<<<4096, 256, 0, stream>>>(bits, f1v, f2v, rmax, isum);
    att_gemm<<<256, 256, 0, stream>>>(bits, f1v, f2v, rmax, isum, Whbt, nullptr, h0);

    // layer 2: A=h0
    proj_gemm<<<256, 256, 0, stream>>>(h0, Wbt + 2 * 65536, Whf, Whbt, nullptr);
    fvec<<<1024, 256, 0, stream>>>(Whf, a2, f1v, f2v);
    stats<<<4096, 256, 0, stream>>>(bits, f1v, f2v, rmax, isum);
    att_gemm<<<256, 256, 0, stream>>>(bits, f1v, f2v, rmax, isum, Whbt, nullptr, h1);

    // layer 3: A=h1, final output
    proj_gemm<<<256, 256, 0, stream>>>(h1, Wbt + 3 * 65536, Whf, Whbt, nullptr);
    fvec<<<1024, 256, 0, stream>>>(Whf, a3, f1v, f2v);
    stats<<<4096, 256, 0, stream>>>(bits, f1v, f2v, rmax, isum);
    att_gemm<<<256, 256, 0, stream>>>(bits, f1v, f2v, rmax, isum, Whbt, out, h0);
}

// Round 2
// 296.034 us; speedup vs baseline: 1.6608x; 1.6608x over previous
//
#include <hip/hip_runtime.h>
#include <hip/hip_bf16.h>
#include <cstdint>
#include <cstddef>

#define NN 4096
#define FD 256
#define WPR 64  // 64-bit words per adjacency row (4096 bits)

typedef __attribute__((ext_vector_type(8))) unsigned short ushort8v;
typedef __attribute__((ext_vector_type(4))) unsigned short ushort4v;
typedef __attribute__((ext_vector_type(8))) short short8;
typedef __attribute__((ext_vector_type(4))) float float4v;

static __device__ __forceinline__ unsigned short f2bf(float x) {
    union { float f; unsigned int u; } v; v.f = x;
    unsigned int r = v.u + 0x7FFFu + ((v.u >> 16) & 1u);
    return (unsigned short)(r >> 16);
}

static __device__ __forceinline__ short8 as_s8(ushort8v v) {
    union { ushort8v u; short8 s; } x; x.u = v; return x.s;
}

// ---------------- pack adjacency into bitmask ----------------
__global__ __launch_bounds__(256) void pack_adj(const int* __restrict__ adj,
                                                unsigned long long* __restrict__ bits) {
    const int row = blockIdx.x;
    const int t = threadIdx.x;
    const int wave = t >> 6, lane = t & 63;
    const int* arow = adj + (size_t)row * NN;
    #pragma unroll
    for (int it = 0; it < NN / 256; ++it) {
        int j = it * 256 + wave * 64 + lane;
        unsigned long long m = __ballot(arow[j] > 0);
        if (lane == 0) bits[(size_t)row * WPR + (it * 4 + wave)] = m;
    }
}

// ---------------- convert 4 weight mats to bf16, transposed [n][k] ----------------
__global__ __launch_bounds__(256) void cvt_w(const float* __restrict__ W0, const float* __restrict__ W1,
                                             const float* __restrict__ W2, const float* __restrict__ W3,
                                             unsigned short* __restrict__ Wbt) {
    int idx = blockIdx.x * 256 + threadIdx.x;       // 0 .. 4*65536
    int mat = idx >> 16;
    int within = idx & 65535;
    int n = within >> 8, k = within & 255;
    const float* W = (mat == 0) ? W0 : (mat == 1) ? W1 : (mat == 2) ? W2 : W3;
    Wbt[idx] = f2bf(W[k * 256 + n]);                // Wbt[mat][n][k] = W[k][n]
}

// ---------------- convert input fp32 -> bf16 row-major ----------------
__global__ __launch_bounds__(256) void cvt_h(const float* __restrict__ x, unsigned short* __restrict__ hb) {
    int idx = blockIdx.x * 256 + threadIdx.x;
    hb[idx] = f2bf(x[idx]);
}

// ---------------- projection GEMM: C[4096][256] = A(bf16[4096][256]) @ B (Wbt [256 n][256 k]) ----------------
// Outputs: Cf (fp32 row-major) and/or Cbt (bf16 [n][4096], via LDS transpose) and/or Crow (bf16 row-major).
__global__ __launch_bounds__(256) void proj_gemm(const unsigned short* __restrict__ A,
                                                 const unsigned short* __restrict__ Bt,
                                                 float* __restrict__ Cf,
                                                 unsigned short* __restrict__ Cbt,
                                                 unsigned short* __restrict__ Crow) {
    const int t = threadIdx.x;
    const int bm = blockIdx.x >> 2, bn = blockIdx.x & 3;
    const int m0 = bm * 64, n0 = bn * 64;
    __shared__ unsigned short smem[64 * 40 * 2];   // As | Bs ; reused as 64x72 transpose buf
    unsigned short* As = smem;
    unsigned short* Bs = smem + 64 * 40;
    const int lane = t & 63, wave = t >> 6;
    const int wm = (wave >> 1) * 32, wn = (wave & 1) * 32;
    const int sr = t >> 2, sc = (t & 3) * 8;
    float4v acc[2][2] = {{{0.f,0.f,0.f,0.f},{0.f,0.f,0.f,0.f}},{{0.f,0.f,0.f,0.f},{0.f,0.f,0.f,0.f}}};

    for (int kk = 0; kk < 256; kk += 32) {
        *(ushort8v*)&As[sr * 40 + sc] = *(const ushort8v*)&A[(size_t)(m0 + sr) * 256 + kk + sc];
        *(ushort8v*)&Bs[sr * 40 + sc] = *(const ushort8v*)&Bt[(size_t)(n0 + sr) * 256 + kk + sc];
        __syncthreads();
        const int kc = (lane >> 4) * 8;
        #pragma unroll
        for (int fm = 0; fm < 2; ++fm) {
            short8 a = as_s8(*(const ushort8v*)&As[(wm + fm * 16 + (lane & 15)) * 40 + kc]);
            #pragma unroll
            for (int fn = 0; fn < 2; ++fn) {
                short8 b = as_s8(*(const ushort8v*)&Bs[(wn + fn * 16 + (lane & 15)) * 40 + kc]);
                acc[fm][fn] = __builtin_amdgcn_mfma_f32_16x16x32_bf16(a, b, acc[fm][fn], 0, 0, 0);
            }
        }
        __syncthreads();
    }

    const int rb = wm + (lane >> 4) * 4;
    const int cb = wn + (lane & 15);
    #pragma unroll
    for (int fm = 0; fm < 2; ++fm)
        #pragma unroll
        for (int fn = 0; fn < 2; ++fn)
            #pragma unroll
            for (int r = 0; r < 4; ++r) {
                int lr = rb + fm * 16 + r;            // local m
                int lc = cb + fn * 16;                // local n
                float v = acc[fm][fn][r];
                if (Cf)   Cf[(size_t)(m0 + lr) * 256 + n0 + lc] = v;
                if (Crow) Crow[(size_t)(m0 + lr) * 256 + n0 + lc] = f2bf(v);
            }

    if (Cbt) {
        // LDS transpose: T[n_local][m_local], stride 72 to dodge bank conflicts
        unsigned short* T = smem;                     // 64*72 = 4608 <= 5120 ushorts
        #pragma unroll
        for (int fm = 0; fm < 2; ++fm)
            #pragma unroll
            for (int fn = 0; fn < 2; ++fn)
                #pragma unroll
                for (int r = 0; r < 4; ++r)
                    T[(cb + fn * 16) * 72 + rb + fm * 16 + r] = f2bf(acc[fm][fn][r]);
        __syncthreads();
        const int tr = t >> 2;                        // n_local 0..63
        #pragma unroll
        for (int i = 0; i < 2; ++i) {
            int tc = (t & 3) * 8 + i * 32;            // m_local
            *(ushort8v*)&Cbt[(size_t)(n0 + tr) * 4096 + m0 + tc] = *(const ushort8v*)&T[tr * 72 + tc];
        }
    }
}

// ---------------- f1/f2: per-row dots of Wh (fp32) with attention vector halves ----------------
__global__ __launch_bounds__(256) void fvec(const float* __restrict__ Wh, const float* __restrict__ a,
                                            float* __restrict__ f1, float* __restrict__ f2) {
    const int wave = threadIdx.x >> 6, lane = threadIdx.x & 63;
    const int i = blockIdx.x * 4 + wave;
    const float* row = Wh + (size_t)i * 256;
    float s1 = 0.f, s2 = 0.f;
    #pragma unroll
    for (int c0 = 0; c0 < 256; c0 += 64) {
        int c = c0 + lane;
        float w = row[c];
        s1 += w * a[c];
        s2 += w * a[256 + c];
    }
    #pragma unroll
    for (int off = 32; off > 0; off >>= 1) {
        s1 += __shfl_down(s1, off, 64);
        s2 += __shfl_down(s2, off, 64);
    }
    if (lane == 0) { f1[i] = s1; f2[i] = s2; }
}

// ---------------- per-row masked softmax stats (online) ----------------
__global__ __launch_bounds__(256) void stats(const unsigned long long* __restrict__ bits,
                                             const float* __restrict__ f1, const float* __restrict__ f2,
                                             float* __restrict__ rowmax, float* __restrict__ invsum) {
    const int i = blockIdx.x;
    const int t = threadIdx.x;
    __shared__ unsigned long long wbits[WPR];
    __shared__ float red_m[256], red_s[256];
    if (t < WPR) wbits[t] = bits[(size_t)i * WPR + t];
    __syncthreads();
    const float f1i = f1[i];
    float m = -3.0e38f, s = 0.f;
    #pragma unroll
    for (int it = 0; it < 16; ++it) {
        int j = it * 256 + t;
        if ((wbits[j >> 6] >> (j & 63)) & 1ULL) {
            float e = f1i + f2[j];
            e = e > 0.f ? e : 0.01f * e;
            if (e > m) { s = s * __expf(m - e) + 1.f; m = e; }
            else       { s += __expf(e - m); }
        }
    }
    red_m[t] = m; red_s[t] = s;
    __syncthreads();
    for (int off = 128; off > 0; off >>= 1) {
        if (t < off) {
            float m2 = red_m[t + off], s2 = red_s[t + off];
            float mo = red_m[t], so = red_s[t];
            float mn = fmaxf(mo, m2);
            red_s[t] = so * __expf(mo - mn) + s2 * __expf(m2 - mn);
            red_m[t] = mn;
        }
        __syncthreads();
    }
    if (t == 0) { rowmax[i] = red_m[0]; invsum[i] = 1.0f / red_s[0]; }
}

// ---------------- attention GEMM, split-K: part[ks] += P(64 rows, Kchunk) @ Wh(Kchunk, 256) ----------------
// Tile: 64 M x 256 N per block, BK=32. Grid = 64 * SPLIT. A tile generated on the fly (dedup'd).
__global__ __launch_bounds__(256, 2) void att_split(const unsigned long long* __restrict__ bits,
                                                    const float* __restrict__ f1, const float* __restrict__ f2,
                                                    const float* __restrict__ rowmax,
                                                    const unsigned short* __restrict__ Bt,  // Whbt [256][4096]
                                                    float* __restrict__ part, int kchunk) {
    const int t = threadIdx.x;
    const int bm = blockIdx.x & 63;
    const int ks = blockIdx.x >> 6;
    const int m0 = bm * 64;
    const int k0 = ks * kchunk;
    __shared__ unsigned short As[64 * 40];     // 5.1 KB
    __shared__ unsigned short Bs[256 * 40];    // 20.5 KB
    const int lane = t & 63, wave = t >> 6;
    const int wn = wave * 64;
    const int sr = t >> 2, sc = (t & 3) * 8;
    const float f1r = f1[m0 + sr];
    const float mr = rowmax[m0 + sr];
    const unsigned long long* brow = bits + (size_t)(m0 + sr) * WPR;
    float4v acc[4][4];
    #pragma unroll
    for (int i = 0; i < 4; ++i)
        #pragma unroll
        for (int j = 0; j < 4; ++j) acc[i][j] = (float4v){0.f, 0.f, 0.f, 0.f};

    for (int kk = k0; kk < k0 + kchunk; kk += 32) {
        // A tile (softmax numerators), each element exactly once per layer
        unsigned long long w = brow[kk >> 6];
        const int sb = (kk & 63) + sc;
        float4v fa = *(const float4v*)&f2[kk + sc];
        float4v fb = *(const float4v*)&f2[kk + sc + 4];
        ushort8v pa;
        #pragma unroll
        for (int jj = 0; jj < 8; ++jj) {
            float e = f1r + ((jj < 4) ? fa[jj] : fb[jj - 4]);
            e = e > 0.f ? e : 0.01f * e;
            float p = ((w >> (sb + jj)) & 1ULL) ? __expf(e - mr) : 0.f;
            pa[jj] = f2bf(p);
        }
        *(ushort8v*)&As[sr * 40 + sc] = pa;
        // B tile: 256 n-rows x 32 k
        #pragma unroll
        for (int i = 0; i < 4; ++i) {
            int r = i * 64 + sr;
            *(ushort8v*)&Bs[r * 40 + sc] = *(const ushort8v*)&Bt[(size_t)r * 4096 + kk + sc];
        }
        __syncthreads();
        const int kc = (lane >> 4) * 8;
        short8 a[4], b[4];
        #pragma unroll
        for (int fm = 0; fm < 4; ++fm)
            a[fm] = as_s8(*(const ushort8v*)&As[(fm * 16 + (lane & 15)) * 40 + kc]);
        #pragma unroll
        for (int fn = 0; fn < 4; ++fn)
            b[fn] = as_s8(*(const ushort8v*)&Bs[(wn + fn * 16 + (lane & 15)) * 40 + kc]);
        #pragma unroll
        for (int fm = 0; fm < 4; ++fm)
            #pragma unroll
            for (int fn = 0; fn < 4; ++fn)
                acc[fm][fn] = __builtin_amdgcn_mfma_f32_16x16x32_bf16(a[fm], b[fn], acc[fm][fn], 0, 0, 0);
        __syncthreads();
    }

    const int rb = (lane >> 4) * 4;
    const int cb = wn + (lane & 15);
    float* pbase = part + ((size_t)ks << 20);    // 4096*256 per split
    #pragma unroll
    for (int fm = 0; fm < 4; ++fm)
        #pragma unroll
        for (int fn = 0; fn < 4; ++fn)
            #pragma unroll
            for (int r = 0; r < 4; ++r)
                pbase[(size_t)(m0 + rb + fm * 16 + r) * 256 + cb + fn * 16] = acc[fm][fn][r];
}

// ---------------- reduce split-K partials, apply 1/rowsum + ELU ----------------
__global__ __launch_bounds__(256) void att_reduce(const float* __restrict__ part,
                                                  const float* __restrict__ invsum,
                                                  float* __restrict__ outf,
                                                  unsigned short* __restrict__ hrow, int nsplit) {
    const int idx = (blockIdx.x * 256 + threadIdx.x) * 4;   // over 4096*256
    const int m = idx >> 8;
    float4v s = *(const float4v*)&part[idx];
    for (int sp = 1; sp < nsplit; ++sp)
        s += *(const float4v*)&part[((size_t)sp << 20) + idx];
    const float inv = invsum[m];
    float4v v;
    ushort4v hb;
    #pragma unroll
    for (int j = 0; j < 4; ++j) {
        float x = s[j] * inv;
        x = x > 0.f ? x : (__expf(x) - 1.f);   // ELU
        v[j] = x;
        hb[j] = f2bf(x);
    }
    if (outf) *(float4v*)&outf[idx] = v;
    *(ushort4v*)&hrow[idx] = hb;
}

extern "C" void kernel_launch(void* const* d_in, const int* in_sizes, int n_in,
                              void* d_out, int out_size, void* d_ws, size_t ws_size,
                              hipStream_t stream) {
    const float* input = (const float*)d_in[0];
    const int*   adj   = (const int*)d_in[1];
    const float* W0    = (const float*)d_in[2];
    const float* W1    = (const float*)d_in[3];
    const float* a1    = (const float*)d_in[4];
    const float* W2    = (const float*)d_in[5];
    const float* a2    = (const float*)d_in[6];
    const float* W3    = (const float*)d_in[7];
    const float* a3    = (const float*)d_in[8];
    float* out = (float*)d_out;
    char* ws = (char*)d_ws;

    unsigned long long* bits = (unsigned long long*)(ws);                 // 2 MB
    unsigned short* h0   = (unsigned short*)(ws + (2u << 20));            // 2 MB bf16 [4096][256]
    unsigned short* h1   = (unsigned short*)(ws + (4u << 20));            // 2 MB
    unsigned short* Whbt = (unsigned short*)(ws + (6u << 20));            // 2 MB bf16 [256][4096]
    float*          Whf  = (float*)(ws + (8u << 20));                     // 4 MB fp32 [4096][256]
    unsigned short* Wbt  = (unsigned short*)(ws + (12u << 20));           // 512 KB (4 mats)
    float* f1v   = (float*)(ws + (12u << 20) + (512u << 10));
    float* f2v   = f1v + 4096;
    float* rmax  = f2v + 4096;
    float* isum  = rmax + 4096;
    float* part  = (float*)(ws + (13u << 20));                            // 4 MB * SPLIT

    // pick split factor by available workspace (deterministic per deployment)
    const size_t base = 13u << 20;
    int SPLIT = 8;
    while (SPLIT > 1 && base + (size_t)SPLIT * (4u << 20) > ws_size) SPLIT >>= 1;
    const int kchunk = NN / SPLIT;

    pack_adj<<<4096, 256, 0, stream>>>(adj, bits);
    cvt_w<<<1024, 256, 0, stream>>>(W0, W1, W2, W3, Wbt);
    cvt_h<<<4096, 256, 0, stream>>>(input, h0);

    // h = input @ W0  -> h1 (bf16 row-major only)
    proj_gemm<<<256, 256, 0, stream>>>(h0, Wbt + 0 * 65536, nullptr, nullptr, h1);

    // layer 1: A=h1 -> h0
    proj_gemm<<<256, 256, 0, stream>>>(h1, Wbt + 1 * 65536, Whf, Whbt, nullptr);
    fvec<<<1024, 256, 0, stream>>>(Whf, a1, f1v, f2v);
    stats<<<4096, 256, 0, stream>>>(bits, f1v, f2v, rmax, isum);
    att_split<<<64 * SPLIT, 256, 0, stream>>>(bits, f1v, f2v, rmax, Whbt, part, kchunk);
    att_reduce<<<1024, 256, 0, stream>>>(part, isum, nullptr, h0, SPLIT);

    // layer 2: A=h0 -> h1
    proj_gemm<<<256, 256, 0, stream>>>(h0, Wbt + 2 * 65536, Whf, Whbt, nullptr);
    fvec<<<1024, 256, 0, stream>>>(Whf, a2, f1v, f2v);
    stats<<<4096, 256, 0, stream>>>(bits, f1v, f2v, rmax, isum);
    att_split<<<64 * SPLIT, 256, 0, stream>>>(bits, f1v, f2v, rmax, Whbt, part, kchunk);
    att_reduce<<<1024, 256, 0, stream>>>(part, isum, nullptr, h1, SPLIT);

    // layer 3: A=h1 -> out (fp32) + h0 (unused)
    proj_gemm<<<256, 256, 0, stream>>>(h1, Wbt + 3 * 65536, Whf, Whbt, nullptr);
    fvec<<<1024, 256, 0, stream>>>(Whf, a3, f1v, f2v);
    stats<<<4096, 256, 0, stream>>>(bits, f1v, f2v, rmax, isum);
    att_split<<<64 * SPLIT, 256, 0, stream>>>(bits, f1v, f2v, rmax, Whbt, part, kchunk);
    att_reduce<<<1024, 256, 0, stream>>>(part, isum, out, h0, SPLIT);
}

// Round 3
// 289.882 us; speedup vs baseline: 1.6960x; 1.0212x over previous
//
#include <hip/hip_runtime.h>
#include <hip/hip_bf16.h>
#include <cstdint>
#include <cstddef>

#define NN 4096
#define FD 256
#define WPR 64  // 64-bit words per adjacency row

typedef __attribute__((ext_vector_type(8))) unsigned short ushort8v;
typedef __attribute__((ext_vector_type(4))) unsigned short ushort4v;
typedef __attribute__((ext_vector_type(8))) short short8;
typedef __attribute__((ext_vector_type(4))) float float4v;

#define C1 30.0f   // fixed shift for eb = exp(f2 - C1); f2 range is O(+-10), safe
#define C2 0.3f    // 0.01 * C1

static __device__ __forceinline__ unsigned short f2bf(float x) {
    union { float f; unsigned int u; } v; v.f = x;
    unsigned int r = v.u + 0x7FFFu + ((v.u >> 16) & 1u);
    return (unsigned short)(r >> 16);
}

static __device__ __forceinline__ short8 as_s8(ushort8v v) {
    union { ushort8v u; short8 s; } x; x.u = v; return x.s;
}

// ---------------- pack adjacency into bitmask ----------------
__global__ __launch_bounds__(256) void pack_adj(const int* __restrict__ adj,
                                                unsigned long long* __restrict__ bits) {
    const int row = blockIdx.x;
    const int t = threadIdx.x;
    const int wave = t >> 6, lane = t & 63;
    const int* arow = adj + (size_t)row * NN;
    #pragma unroll
    for (int it = 0; it < NN / 256; ++it) {
        int j = it * 256 + wave * 64 + lane;
        unsigned long long m = __ballot(arow[j] > 0);
        if (lane == 0) bits[(size_t)row * WPR + (it * 4 + wave)] = m;
    }
}

// ---------------- convert 4 weight mats to bf16, transposed [n][k] ----------------
__global__ __launch_bounds__(256) void cvt_w(const float* __restrict__ W0, const float* __restrict__ W1,
                                             const float* __restrict__ W2, const float* __restrict__ W3,
                                             unsigned short* __restrict__ Wbt) {
    int idx = blockIdx.x * 256 + threadIdx.x;
    int mat = idx >> 16;
    int within = idx & 65535;
    int n = within >> 8, k = within & 255;
    const float* W = (mat == 0) ? W0 : (mat == 1) ? W1 : (mat == 2) ? W2 : W3;
    Wbt[idx] = f2bf(W[k * 256 + n]);
}

// ---------------- convert input fp32 -> bf16 row-major ----------------
__global__ __launch_bounds__(256) void cvt_h(const float* __restrict__ x, unsigned short* __restrict__ hb) {
    int idx = blockIdx.x * 256 + threadIdx.x;
    hb[idx] = f2bf(x[idx]);
}

// ---------------- projection GEMM, full-K LDS (single barrier) ----------------
// C[4096][256] = A(bf16[4096][256]) @ Wbt([256 n][256 k])
__global__ __launch_bounds__(256) void proj_gemm(const unsigned short* __restrict__ A,
                                                 const unsigned short* __restrict__ Bt,
                                                 float* __restrict__ Cf,
                                                 unsigned short* __restrict__ Cbt,
                                                 unsigned short* __restrict__ Crow) {
    const int t = threadIdx.x;
    const int bm = blockIdx.x >> 2, bn = blockIdx.x & 3;
    const int m0 = bm * 64, n0 = bn * 64;
    __shared__ unsigned short As[64 * 264];
    __shared__ unsigned short Bs[64 * 264];
    const int lane = t & 63, wave = t >> 6;
    const int wm = (wave >> 1) * 32, wn = (wave & 1) * 32;
    const int lr = t >> 2, lc0 = (t & 3) * 8;
    #pragma unroll
    for (int i = 0; i < 8; ++i) {
        int col = lc0 + i * 32;
        *(ushort8v*)&As[lr * 264 + col] = *(const ushort8v*)&A[(size_t)(m0 + lr) * 256 + col];
        *(ushort8v*)&Bs[lr * 264 + col] = *(const ushort8v*)&Bt[(size_t)(n0 + lr) * 256 + col];
    }
    __syncthreads();
    float4v acc[2][2] = {{{0.f,0.f,0.f,0.f},{0.f,0.f,0.f,0.f}},{{0.f,0.f,0.f,0.f},{0.f,0.f,0.f,0.f}}};
    #pragma unroll
    for (int kk = 0; kk < 256; kk += 32) {
        const int kc = kk + (lane >> 4) * 8;
        #pragma unroll
        for (int fm = 0; fm < 2; ++fm) {
            short8 a = as_s8(*(const ushort8v*)&As[(wm + fm * 16 + (lane & 15)) * 264 + kc]);
            #pragma unroll
            for (int fn = 0; fn < 2; ++fn) {
                short8 b = as_s8(*(const ushort8v*)&Bs[(wn + fn * 16 + (lane & 15)) * 264 + kc]);
                acc[fm][fn] = __builtin_amdgcn_mfma_f32_16x16x32_bf16(a, b, acc[fm][fn], 0, 0, 0);
            }
        }
    }

    const int rb = wm + (lane >> 4) * 4;
    const int cb = wn + (lane & 15);
    #pragma unroll
    for (int fm = 0; fm < 2; ++fm)
        #pragma unroll
        for (int fn = 0; fn < 2; ++fn)
            #pragma unroll
            for (int r = 0; r < 4; ++r) {
                int lr2 = rb + fm * 16 + r;
                int lc2 = cb + fn * 16;
                float v = acc[fm][fn][r];
                if (Cf)   Cf[(size_t)(m0 + lr2) * 256 + n0 + lc2] = v;
                if (Crow) Crow[(size_t)(m0 + lr2) * 256 + n0 + lc2] = f2bf(v);
            }

    if (Cbt) {
        unsigned short* T = As;                 // reuse, 64x72 fits
        __syncthreads();
        #pragma unroll
        for (int fm = 0; fm < 2; ++fm)
            #pragma unroll
            for (int fn = 0; fn < 2; ++fn)
                #pragma unroll
                for (int r = 0; r < 4; ++r)
                    T[(cb + fn * 16) * 72 + rb + fm * 16 + r] = f2bf(acc[fm][fn][r]);
        __syncthreads();
        const int tr = t >> 2;
        #pragma unroll
        for (int i = 0; i < 2; ++i) {
            int tc = (t & 3) * 8 + i * 32;
            *(ushort8v*)&Cbt[(size_t)(n0 + tr) * 4096 + m0 + tc] = *(const ushort8v*)&T[tr * 72 + tc];
        }
    }
}

// ---------------- f1 + exp tables: f1_i, tab[i] = (exp(f2-C1), exp(0.01 f2 - C2)) ----------------
__global__ __launch_bounds__(256) void fvec(const float* __restrict__ Wh, const float* __restrict__ a,
                                            float* __restrict__ f1, float* __restrict__ tabf) {
    const int wave = threadIdx.x >> 6, lane = threadIdx.x & 63;
    const int i = blockIdx.x * 4 + wave;
    const float* row = Wh + (size_t)i * 256;
    float s1 = 0.f, s2 = 0.f;
    #pragma unroll
    for (int c0 = 0; c0 < 256; c0 += 64) {
        int c = c0 + lane;
        float w = row[c];
        s1 += w * a[c];
        s2 += w * a[256 + c];
    }
    #pragma unroll
    for (int off = 32; off > 0; off >>= 1) {
        s1 += __shfl_down(s1, off, 64);
        s2 += __shfl_down(s2, off, 64);
    }
    if (lane == 0) {
        f1[i] = s1;
        tabf[2 * i]     = __expf(s2 - C1);
        tabf[2 * i + 1] = __expf(0.01f * s2 - C2);
    }
}

// ---------------- per-row coefficients: pA, pG, thresh (no per-pair exp) ----------------
__global__ __launch_bounds__(256) void rowcoef(const unsigned long long* __restrict__ bits,
                                               const float* __restrict__ f1,
                                               const float2* __restrict__ tab,
                                               float4* __restrict__ rowco) {
    __shared__ float2 tl[4096];
    const int t = threadIdx.x;
    #pragma unroll
    for (int i = 0; i < 16; ++i) tl[i * 256 + t] = tab[i * 256 + t];
    __syncthreads();
    const int lane = t & 63, wave = t >> 6;
    for (int rr = 0; rr < 2; ++rr) {
        const int row = blockIdx.x * 8 + wave * 2 + rr;
        const unsigned long long wl = bits[(size_t)row * WPR + lane];
        const float f1r = f1[row];
        const float th = __expf(-f1r - C1);
        float mx = 0.f, S1 = 0.f, S2 = 0.f;
        #pragma unroll 16
        for (int b = 0; b < 64; ++b) {
            unsigned long long w = __shfl(wl, b, 64);
            bool bit = (w >> lane) & 1ULL;
            float2 v = tl[b * 64 + lane];
            float ebm = bit ? v.x : 0.f;
            mx = fmaxf(mx, ebm);
            bool cond = v.x > th;
            S1 += (bit && cond)  ? v.x : 0.f;
            S2 += (bit && !cond) ? v.y : 0.f;
        }
        #pragma unroll
        for (int off = 1; off < 64; off <<= 1) {
            mx = fmaxf(mx, __shfl_xor(mx, off, 64));
            S1 += __shfl_xor(S1, off, 64);
            S2 += __shfl_xor(S2, off, 64);
        }
        if (lane == 0) {
            float M  = C1 + __logf(mx);                  // masked max of f2
            float fm_ = f1r + M;
            float m  = fm_ > 0.f ? fm_ : 0.01f * fm_;    // lrelu
            float alpha = __expf(fminf(f1r + C1 - m, 60.f));
            float gamma = __expf(fminf(0.01f * (f1r + C1) - m, 60.f));
            float inv = 1.0f / (alpha * S1 + gamma * S2);
            rowco[row] = make_float4(alpha * inv, gamma * inv, th, 0.f);
        }
    }
}

// ---------------- attention GEMM, split-K, BK=64, normalized A on the fly ----------------
__global__ __launch_bounds__(256, 2) void att_split(const unsigned long long* __restrict__ bits,
                                                    const float4* __restrict__ rowco,
                                                    const float* __restrict__ tabf,
                                                    const unsigned short* __restrict__ Bt,  // Whbt [256][4096]
                                                    float* __restrict__ part, int kchunk) {
    const int t = threadIdx.x;
    const int bm = blockIdx.x & 63;
    const int ks = blockIdx.x >> 6;
    const int m0 = bm * 64;
    const int k0 = ks * kchunk;
    __shared__ unsigned short As[64 * 72];
    __shared__ unsigned short Bs[256 * 72];
    const int lane = t & 63, wave = t >> 6;
    const int wn = wave * 64;
    const int sr = t >> 2, q = t & 3, sc = q * 16;
    const float4 rc = rowco[m0 + sr];
    const float pA = rc.x, pG = rc.y, th = rc.z;
    const unsigned long long* brow = bits + (size_t)(m0 + sr) * WPR;
    float4v acc[4][4];
    #pragma unroll
    for (int i = 0; i < 4; ++i)
        #pragma unroll
        for (int j = 0; j < 4; ++j) acc[i][j] = (float4v){0.f, 0.f, 0.f, 0.f};

    for (int kk = k0; kk < k0 + kchunk; kk += 64) {
        const unsigned int wb = (unsigned int)(brow[kk >> 6] >> sc) & 0xFFFFu;
        // table slab: 16 (eb,ed) pairs = 32 floats, L1-broadcast across the block
        float tv[32];
        {
            const float4v* tp = (const float4v*)&tabf[2 * (kk + sc)];
            #pragma unroll
            for (int i = 0; i < 8; ++i) {
                float4v x = tp[i];
                tv[4 * i] = x[0]; tv[4 * i + 1] = x[1]; tv[4 * i + 2] = x[2]; tv[4 * i + 3] = x[3];
            }
        }
        ushort8v pa0, pa1;
        #pragma unroll
        for (int jj = 0; jj < 16; ++jj) {
            float eb = tv[2 * jj], ed = tv[2 * jj + 1];
            bool cond = eb > th;
            float val  = cond ? eb : ed;
            float coef = cond ? pA : pG;
            float p = ((wb >> jj) & 1u) ? coef * val : 0.f;
            unsigned short pb = f2bf(p);
            if (jj < 8) pa0[jj] = pb; else pa1[jj - 8] = pb;
        }
        *(ushort8v*)&As[sr * 72 + sc]     = pa0;
        *(ushort8v*)&As[sr * 72 + sc + 8] = pa1;
        #pragma unroll
        for (int i = 0; i < 4; ++i) {
            int r = i * 64 + sr;
            *(ushort8v*)&Bs[r * 72 + sc]     = *(const ushort8v*)&Bt[(size_t)r * 4096 + kk + sc];
            *(ushort8v*)&Bs[r * 72 + sc + 8] = *(const ushort8v*)&Bt[(size_t)r * 4096 + kk + sc + 8];
        }
        __syncthreads();
        #pragma unroll
        for (int half = 0; half < 2; ++half) {
            const int kc = half * 32 + (lane >> 4) * 8;
            short8 a[4], b[4];
            #pragma unroll
            for (int fm = 0; fm < 4; ++fm)
                a[fm] = as_s8(*(const ushort8v*)&As[(fm * 16 + (lane & 15)) * 72 + kc]);
            #pragma unroll
            for (int fn = 0; fn < 4; ++fn)
                b[fn] = as_s8(*(const ushort8v*)&Bs[(wn + fn * 16 + (lane & 15)) * 72 + kc]);
            #pragma unroll
            for (int fm = 0; fm < 4; ++fm)
                #pragma unroll
                for (int fn = 0; fn < 4; ++fn)
                    acc[fm][fn] = __builtin_amdgcn_mfma_f32_16x16x32_bf16(a[fm], b[fn], acc[fm][fn], 0, 0, 0);
        }
        __syncthreads();
    }

    const int rb = (lane >> 4) * 4;
    const int cb = wn + (lane & 15);
    float* pbase = part + ((size_t)ks << 20);
    #pragma unroll
    for (int fm = 0; fm < 4; ++fm)
        #pragma unroll
        for (int fn = 0; fn < 4; ++fn)
            #pragma unroll
            for (int r = 0; r < 4; ++r)
                pbase[(size_t)(m0 + rb + fm * 16 + r) * 256 + cb + fn * 16] = acc[fm][fn][r];
}

// ---------------- reduce split-K partials + ELU (P already normalized) ----------------
__global__ __launch_bounds__(256) void att_reduce(const float* __restrict__ part,
                                                  float* __restrict__ outf,
                                                  unsigned short* __restrict__ hrow, int nsplit) {
    const int idx = (blockIdx.x * 256 + threadIdx.x) * 4;
    float4v s = *(const float4v*)&part[idx];
    for (int sp = 1; sp < nsplit; ++sp)
        s += *(const float4v*)&part[((size_t)sp << 20) + idx];
    float4v v;
    ushort4v hb;
    #pragma unroll
    for (int j = 0; j < 4; ++j) {
        float x = s[j];
        x = x > 0.f ? x : (__expf(x) - 1.f);
        v[j] = x;
        hb[j] = f2bf(x);
    }
    if (outf) *(float4v*)&outf[idx] = v;
    *(ushort4v*)&hrow[idx] = hb;
}

extern "C" void kernel_launch(void* const* d_in, const int* in_sizes, int n_in,
                              void* d_out, int out_size, void* d_ws, size_t ws_size,
                              hipStream_t stream) {
    const float* input = (const float*)d_in[0];
    const int*   adj   = (const int*)d_in[1];
    const float* W0    = (const float*)d_in[2];
    const float* W1    = (const float*)d_in[3];
    const float* a1    = (const float*)d_in[4];
    const float* W2    = (const float*)d_in[5];
    const float* a2    = (const float*)d_in[6];
    const float* W3    = (const float*)d_in[7];
    const float* a3    = (const float*)d_in[8];
    float* out = (float*)d_out;
    char* ws = (char*)d_ws;

    unsigned long long* bits = (unsigned long long*)(ws);                 // 2 MB
    unsigned short* h0   = (unsigned short*)(ws + (2u << 20));            // 2 MB
    unsigned short* h1   = (unsigned short*)(ws + (4u << 20));            // 2 MB
    unsigned short* Whbt = (unsigned short*)(ws + (6u << 20));            // 2 MB
    float*          Whf  = (float*)(ws + (8u << 20));                     // 4 MB
    unsigned short* Wbt  = (unsigned short*)(ws + (12u << 20));           // 512 KB
    float*  f1v   = (float*)(ws + (12u << 20) + (512u << 10));            // 16 KB
    float*  tabf  = f1v + 4096;                                           // 32 KB (float2[4096])
    float4* rowco = (float4*)(tabf + 8192);                               // 64 KB
    float*  part  = (float*)(ws + (13u << 20));                           // 4 MB * SPLIT

    const size_t base = 13u << 20;
    int SPLIT = 8;
    while (SPLIT > 1 && base + (size_t)SPLIT * (4u << 20) > ws_size) SPLIT >>= 1;
    const int kchunk = NN / SPLIT;

    pack_adj<<<4096, 256, 0, stream>>>(adj, bits);
    cvt_w<<<1024, 256, 0, stream>>>(W0, W1, W2, W3, Wbt);
    cvt_h<<<4096, 256, 0, stream>>>(input, h0);

    proj_gemm<<<256, 256, 0, stream>>>(h0, Wbt + 0 * 65536, nullptr, nullptr, h1);

    // layer 1
    proj_gemm<<<256, 256, 0, stream>>>(h1, Wbt + 1 * 65536, Whf, Whbt, nullptr);
    fvec<<<1024, 256, 0, stream>>>(Whf, a1, f1v, tabf);
    rowcoef<<<512, 256, 0, stream>>>(bits, f1v, (const float2*)tabf, rowco);
    att_split<<<64 * SPLIT, 256, 0, stream>>>(bits, rowco, tabf, Whbt, part, kchunk);
    att_reduce<<<1024, 256, 0, stream>>>(part, nullptr, h0, SPLIT);

    // layer 2
    proj_gemm<<<256, 256, 0, stream>>>(h0, Wbt + 2 * 65536, Whf, Whbt, nullptr);
    fvec<<<1024, 256, 0, stream>>>(Whf, a2, f1v, tabf);
    rowcoef<<<512, 256, 0, stream>>>(bits, f1v, (const float2*)tabf, rowco);
    att_split<<<64 * SPLIT, 256, 0, stream>>>(bits, rowco, tabf, Whbt, part, kchunk);
    att_reduce<<<1024, 256, 0, stream>>>(part, nullptr, h1, SPLIT);

    // layer 3
    proj_gemm<<<256, 256, 0, stream>>>(h1, Wbt + 3 * 65536, Whf, Whbt, nullptr);
    fvec<<<1024, 256, 0, stream>>>(Whf, a3, f1v, tabf);
    rowcoef<<<512, 256, 0, stream>>>(bits, f1v, (const float2*)tabf, rowco);
    att_split<<<64 * SPLIT, 256, 0, stream>>>(bits, rowco, tabf, Whbt, part, kchunk);
    att_reduce<<<1024, 256, 0, stream>>>(part, out, h0, SPLIT);
}

// Round 4
// 287.186 us; speedup vs baseline: 1.7120x; 1.0094x over previous
//
#include <hip/hip_runtime.h>
#include <hip/hip_bf16.h>
#include <cstdint>
#include <cstddef>

#define NN 4096
#define FD 256
#define WPR 64  // 64-bit words per adjacency row

typedef __attribute__((ext_vector_type(8))) unsigned short ushort8v;
typedef __attribute__((ext_vector_type(4))) unsigned short ushort4v;
typedef __attribute__((ext_vector_type(8))) short short8;
typedef __attribute__((ext_vector_type(4))) float float4v;

#define C1 30.0f
#define C2 0.3f    // 0.01 * C1

static __device__ __forceinline__ unsigned short f2bf(float x) {
    union { float f; unsigned int u; } v; v.f = x;
    unsigned int r = v.u + 0x7FFFu + ((v.u >> 16) & 1u);
    return (unsigned short)(r >> 16);
}

static __device__ __forceinline__ short8 as_s8(ushort8v v) {
    union { ushort8v u; short8 s; } x; x.u = v; return x.s;
}

// ---------------- fused setup: pack adj + cvt input + cvt weights + zero f1f2 ----------------
__global__ __launch_bounds__(256) void setup(const int* __restrict__ adj,
                                             const float* __restrict__ input,
                                             const float* __restrict__ W0, const float* __restrict__ W1,
                                             const float* __restrict__ W2, const float* __restrict__ W3,
                                             unsigned long long* __restrict__ bits,
                                             unsigned short* __restrict__ hb,
                                             unsigned short* __restrict__ Wbt,
                                             float* __restrict__ f1f2) {
    const int b = blockIdx.x;
    const int t = threadIdx.x;
    if (b < 4096) {
        const int wave = t >> 6, lane = t & 63;
        const int* arow = adj + (size_t)b * NN;
        #pragma unroll
        for (int it = 0; it < NN / 256; ++it) {
            int j = it * 256 + wave * 64 + lane;
            unsigned long long m = __ballot(arow[j] > 0);
            if (lane == 0) bits[(size_t)b * WPR + (it * 4 + wave)] = m;
        }
        hb[(size_t)b * 256 + t] = f2bf(input[(size_t)b * 256 + t]);
    } else if (b < 5120) {
        int idx = (b - 4096) * 256 + t;          // 0 .. 4*65536
        int mat = idx >> 16;
        int within = idx & 65535;
        int n = within >> 8, k = within & 255;
        const float* W = (mat == 0) ? W0 : (mat == 1) ? W1 : (mat == 2) ? W2 : W3;
        Wbt[idx] = f2bf(W[k * 256 + n]);
    } else {
        // zero 3 layers x 8192 floats of f1/f2
        #pragma unroll
        for (int i = 0; i < 24; ++i) {
            int pos = i * 1024 + (b - 5120) * 256 + t;
            f1f2[pos] = 0.f;
        }
    }
}

// ---------------- projection GEMM, full-K LDS; epilogue: Cbt/Crow + f1/f2 atomics ----------------
__global__ __launch_bounds__(256) void proj_gemm(const unsigned short* __restrict__ A,
                                                 const unsigned short* __restrict__ Bt,
                                                 const float* __restrict__ av,     // attention vec [512] or null
                                                 float* __restrict__ f1f2,         // f1[4096], f2[4096] or null
                                                 unsigned short* __restrict__ Cbt, // bf16 [n][4096] or null
                                                 unsigned short* __restrict__ Crow) {
    const int t = threadIdx.x;
    const int bm = blockIdx.x >> 2, bn = blockIdx.x & 3;
    const int m0 = bm * 64, n0 = bn * 64;
    __shared__ unsigned short As[64 * 264];
    __shared__ unsigned short Bs[64 * 264];
    const int lane = t & 63, wave = t >> 6;
    const int wm = (wave >> 1) * 32, wn = (wave & 1) * 32;
    const int lr = t >> 2, lc0 = (t & 3) * 8;
    #pragma unroll
    for (int i = 0; i < 8; ++i) {
        int col = lc0 + i * 32;
        *(ushort8v*)&As[lr * 264 + col] = *(const ushort8v*)&A[(size_t)(m0 + lr) * 256 + col];
        *(ushort8v*)&Bs[lr * 264 + col] = *(const ushort8v*)&Bt[(size_t)(n0 + lr) * 256 + col];
    }
    __syncthreads();
    float4v acc[2][2] = {{{0.f,0.f,0.f,0.f},{0.f,0.f,0.f,0.f}},{{0.f,0.f,0.f,0.f},{0.f,0.f,0.f,0.f}}};
    #pragma unroll
    for (int kk = 0; kk < 256; kk += 32) {
        const int kc = kk + (lane >> 4) * 8;
        #pragma unroll
        for (int fm = 0; fm < 2; ++fm) {
            short8 a = as_s8(*(const ushort8v*)&As[(wm + fm * 16 + (lane & 15)) * 264 + kc]);
            #pragma unroll
            for (int fn = 0; fn < 2; ++fn) {
                short8 b = as_s8(*(const ushort8v*)&Bs[(wn + fn * 16 + (lane & 15)) * 264 + kc]);
                acc[fm][fn] = __builtin_amdgcn_mfma_f32_16x16x32_bf16(a, b, acc[fm][fn], 0, 0, 0);
            }
        }
    }

    const int rb = wm + (lane >> 4) * 4;
    const int cb = wn + (lane & 15);
    if (Crow) {
        #pragma unroll
        for (int fm = 0; fm < 2; ++fm)
            #pragma unroll
            for (int fn = 0; fn < 2; ++fn)
                #pragma unroll
                for (int r = 0; r < 4; ++r)
                    Crow[(size_t)(m0 + rb + fm * 16 + r) * 256 + n0 + cb + fn * 16] = f2bf(acc[fm][fn][r]);
    }

    if (f1f2) {
        float a1c[2], a2c[2];
        #pragma unroll
        for (int fn = 0; fn < 2; ++fn) {
            a1c[fn] = av[n0 + cb + fn * 16];
            a2c[fn] = av[256 + n0 + cb + fn * 16];
        }
        #pragma unroll
        for (int fm = 0; fm < 2; ++fm)
            #pragma unroll
            for (int r = 0; r < 4; ++r) {
                float s1 = acc[fm][0][r] * a1c[0] + acc[fm][1][r] * a1c[1];
                float s2 = acc[fm][0][r] * a2c[0] + acc[fm][1][r] * a2c[1];
                #pragma unroll
                for (int off = 1; off < 16; off <<= 1) {
                    s1 += __shfl_xor(s1, off, 64);
                    s2 += __shfl_xor(s2, off, 64);
                }
                if ((lane & 15) == 0) {
                    int row = m0 + rb + fm * 16 + r;
                    atomicAdd(&f1f2[row], s1);
                    atomicAdd(&f1f2[4096 + row], s2);
                }
            }
    }

    if (Cbt) {
        unsigned short* T = As;
        __syncthreads();
        #pragma unroll
        for (int fm = 0; fm < 2; ++fm)
            #pragma unroll
            for (int fn = 0; fn < 2; ++fn)
                #pragma unroll
                for (int r = 0; r < 4; ++r)
                    T[(cb + fn * 16) * 72 + rb + fm * 16 + r] = f2bf(acc[fm][fn][r]);
        __syncthreads();
        const int tr = t >> 2;
        #pragma unroll
        for (int i = 0; i < 2; ++i) {
            int tc = (t & 3) * 8 + i * 32;
            *(ushort8v*)&Cbt[(size_t)(n0 + tr) * 4096 + m0 + tc] = *(const ushort8v*)&T[tr * 72 + tc];
        }
    }
}

// ---------------- per-row coefficients: pA, pG, -f1 (no per-pair exp in scan) ----------------
__global__ __launch_bounds__(256) void rowcoef(const unsigned long long* __restrict__ bits,
                                               const float* __restrict__ f1f2,
                                               float4* __restrict__ rowco) {
    __shared__ float2 tl[4096];
    const int t = threadIdx.x;
    const float* f2p = f1f2 + 4096;
    #pragma unroll
    for (int i = 0; i < 16; ++i) {
        float v = f2p[i * 256 + t];
        tl[i * 256 + t] = make_float2(__expf(v - C1), __expf(0.01f * v - C2));
    }
    __syncthreads();
    const int lane = t & 63, wave = t >> 6;
    for (int rr = 0; rr < 2; ++rr) {
        const int row = blockIdx.x * 8 + wave * 2 + rr;
        const unsigned long long wl = bits[(size_t)row * WPR + lane];
        const float f1r = f1f2[row];
        const float th = __expf(-f1r - C1);
        float mx = 0.f, S1 = 0.f, S2 = 0.f;
        #pragma unroll 16
        for (int b = 0; b < 64; ++b) {
            unsigned long long w = __shfl(wl, b, 64);
            bool bit = (w >> lane) & 1ULL;
            float2 v = tl[b * 64 + lane];
            float ebm = bit ? v.x : 0.f;
            mx = fmaxf(mx, ebm);
            bool cond = v.x > th;
            S1 += (bit && cond)  ? v.x : 0.f;
            S2 += (bit && !cond) ? v.y : 0.f;
        }
        #pragma unroll
        for (int off = 1; off < 64; off <<= 1) {
            mx = fmaxf(mx, __shfl_xor(mx, off, 64));
            S1 += __shfl_xor(S1, off, 64);
            S2 += __shfl_xor(S2, off, 64);
        }
        if (lane == 0) {
            float M  = C1 + __logf(mx);
            float fm_ = f1r + M;
            float m  = fm_ > 0.f ? fm_ : 0.01f * fm_;    // lrelu
            float alpha = __expf(fminf(f1r + C1 - m, 60.f));
            float gamma = __expf(fminf(0.01f * (f1r + C1) - m, 60.f));
            float inv = 1.0f / (alpha * S1 + gamma * S2);
            rowco[row] = make_float4(alpha * inv, gamma * inv, -f1r, 0.f);
        }
    }
}

// ---------------- attention GEMM, split-K, BK=64: A via LDS, B direct from global ----------------
__global__ __launch_bounds__(256, 2) void att_split(const unsigned long long* __restrict__ bits,
                                                    const float4* __restrict__ rowco,
                                                    const float* __restrict__ f1f2,
                                                    const unsigned short* __restrict__ Bt,  // Whbt [256][4096]
                                                    float* __restrict__ part, int kchunk) {
    const int t = threadIdx.x;
    const int bm = blockIdx.x & 63;
    const int ks = blockIdx.x >> 6;
    const int m0 = bm * 64;
    const int k0 = ks * kchunk;
    __shared__ unsigned short As[64 * 72];     // 9.2 KB
    const int lane = t & 63, wave = t >> 6;
    const int wn = wave * 64;
    const int sr = t >> 2, sc = (t & 3) * 16;
    const float4 rc = rowco[m0 + sr];
    const float pA = rc.x, pG = rc.y, thf2 = rc.z;
    const unsigned long long* brow = bits + (size_t)(m0 + sr) * WPR;
    const float* f2p = f1f2 + 4096;
    // per-lane B base: row = wn + fn*16 + (lane&15), k offset (lane>>4)*8
    const unsigned short* bbase = Bt + (size_t)(wn + (lane & 15)) * 4096 + (lane >> 4) * 8;
    float4v acc[4][4];
    #pragma unroll
    for (int i = 0; i < 4; ++i)
        #pragma unroll
        for (int j = 0; j < 4; ++j) acc[i][j] = (float4v){0.f, 0.f, 0.f, 0.f};

    for (int kk = k0; kk < k0 + kchunk; kk += 64) {
        // ---- generate 16 normalized-P elements for row sr (one exp each) ----
        const unsigned int wb = (unsigned int)(brow[kk >> 6] >> sc) & 0xFFFFu;
        float fv[16];
        {
            const float4v* fp = (const float4v*)&f2p[kk + sc];
            #pragma unroll
            for (int i = 0; i < 4; ++i) {
                float4v x = fp[i];
                fv[4 * i] = x[0]; fv[4 * i + 1] = x[1]; fv[4 * i + 2] = x[2]; fv[4 * i + 3] = x[3];
            }
        }
        ushort8v pa0, pa1;
        #pragma unroll
        for (int jj = 0; jj < 16; ++jj) {
            float f2j = fv[jj];
            bool cond = f2j > thf2;
            float arg  = cond ? (f2j - C1) : (0.01f * f2j - C2);
            float coef = cond ? pA : pG;
            float p = ((wb >> jj) & 1u) ? coef * __expf(arg) : 0.f;
            unsigned short pb = f2bf(p);
            if (jj < 8) pa0[jj] = pb; else pa1[jj - 8] = pb;
        }
        *(ushort8v*)&As[sr * 72 + sc]     = pa0;
        *(ushort8v*)&As[sr * 72 + sc + 8] = pa1;
        // ---- B fragments direct from global (no barrier dependency) ----
        ushort8v breg[4][2];
        #pragma unroll
        for (int fn = 0; fn < 4; ++fn)
            #pragma unroll
            for (int half = 0; half < 2; ++half)
                breg[fn][half] = *(const ushort8v*)&bbase[(size_t)(fn * 16) * 4096 + kk + half * 32];
        __syncthreads();
        #pragma unroll
        for (int half = 0; half < 2; ++half) {
            const int kc = half * 32 + (lane >> 4) * 8;
            short8 a[4];
            #pragma unroll
            for (int fm = 0; fm < 4; ++fm)
                a[fm] = as_s8(*(const ushort8v*)&As[(fm * 16 + (lane & 15)) * 72 + kc]);
            #pragma unroll
            for (int fm = 0; fm < 4; ++fm)
                #pragma unroll
                for (int fn = 0; fn < 4; ++fn)
                    acc[fm][fn] = __builtin_amdgcn_mfma_f32_16x16x32_bf16(a[fm], as_s8(breg[fn][half]), acc[fm][fn], 0, 0, 0);
        }
        __syncthreads();
    }

    const int rb = (lane >> 4) * 4;
    const int cb = wn + (lane & 15);
    float* pbase = part + ((size_t)ks << 20);
    #pragma unroll
    for (int fm = 0; fm < 4; ++fm)
        #pragma unroll
        for (int fn = 0; fn < 4; ++fn)
            #pragma unroll
            for (int r = 0; r < 4; ++r)
                pbase[(size_t)(m0 + rb + fm * 16 + r) * 256 + cb + fn * 16] = acc[fm][fn][r];
}

// ---------------- reduce split-K partials + ELU (P already normalized) ----------------
__global__ __launch_bounds__(256) void att_reduce(const float* __restrict__ part,
                                                  float* __restrict__ outf,
                                                  unsigned short* __restrict__ hrow, int nsplit) {
    const int idx = (blockIdx.x * 256 + threadIdx.x) * 4;
    float4v s = *(const float4v*)&part[idx];
    for (int sp = 1; sp < nsplit; ++sp)
        s += *(const float4v*)&part[((size_t)sp << 20) + idx];
    float4v v;
    ushort4v hb;
    #pragma unroll
    for (int j = 0; j < 4; ++j) {
        float x = s[j];
        x = x > 0.f ? x : (__expf(x) - 1.f);
        v[j] = x;
        hb[j] = f2bf(x);
    }
    if (outf) *(float4v*)&outf[idx] = v;
    *(ushort4v*)&hrow[idx] = hb;
}

extern "C" void kernel_launch(void* const* d_in, const int* in_sizes, int n_in,
                              void* d_out, int out_size, void* d_ws, size_t ws_size,
                              hipStream_t stream) {
    const float* input = (const float*)d_in[0];
    const int*   adj   = (const int*)d_in[1];
    const float* W0    = (const float*)d_in[2];
    const float* W1    = (const float*)d_in[3];
    const float* a1    = (const float*)d_in[4];
    const float* W2    = (const float*)d_in[5];
    const float* a2    = (const float*)d_in[6];
    const float* W3    = (const float*)d_in[7];
    const float* a3    = (const float*)d_in[8];
    float* out = (float*)d_out;
    char* ws = (char*)d_ws;

    unsigned long long* bits = (unsigned long long*)(ws);                 // 2 MB
    unsigned short* h0   = (unsigned short*)(ws + (2u << 20));            // 2 MB
    unsigned short* h1   = (unsigned short*)(ws + (4u << 20));            // 2 MB
    unsigned short* Whbt = (unsigned short*)(ws + (6u << 20));            // 2 MB
    unsigned short* Wbt  = (unsigned short*)(ws + (8u << 20));            // 512 KB
    float*  f1f2  = (float*)(ws + (9u << 20));                            // 3 layers x 32 KB
    float4* rowco = (float4*)(ws + (10u << 20));                          // 64 KB
    float*  part  = (float*)(ws + (13u << 20));                           // 4 MB * SPLIT

    const size_t base = 13u << 20;
    int SPLIT = 8;
    while (SPLIT > 1 && base + (size_t)SPLIT * (4u << 20) > ws_size) SPLIT >>= 1;
    const int kchunk = NN / SPLIT;

    float* f1f2_l[3] = { f1f2, f1f2 + 8192, f1f2 + 16384 };

    setup<<<5124, 256, 0, stream>>>(adj, input, W0, W1, W2, W3, bits, h0, Wbt, f1f2);

    // h = input @ W0 -> h1
    proj_gemm<<<256, 256, 0, stream>>>(h0, Wbt + 0 * 65536, nullptr, nullptr, nullptr, h1);

    // layer 1
    proj_gemm<<<256, 256, 0, stream>>>(h1, Wbt + 1 * 65536, a1, f1f2_l[0], Whbt, nullptr);
    rowcoef<<<512, 256, 0, stream>>>(bits, f1f2_l[0], rowco);
    att_split<<<64 * SPLIT, 256, 0, stream>>>(bits, rowco, f1f2_l[0], Whbt, part, kchunk);
    att_reduce<<<1024, 256, 0, stream>>>(part, nullptr, h0, SPLIT);

    // layer 2
    proj_gemm<<<256, 256, 0, stream>>>(h0, Wbt + 2 * 65536, a2, f1f2_l[1], Whbt, nullptr);
    rowcoef<<<512, 256, 0, stream>>>(bits, f1f2_l[1], rowco);
    att_split<<<64 * SPLIT, 256, 0, stream>>>(bits, rowco, f1f2_l[1], Whbt, part, kchunk);
    att_reduce<<<1024, 256, 0, stream>>>(part, nullptr, h1, SPLIT);

    // layer 3
    proj_gemm<<<256, 256, 0, stream>>>(h1, Wbt + 3 * 65536, a3, f1f2_l[2], Whbt, nullptr);
    rowcoef<<<512, 256, 0, stream>>>(bits, f1f2_l[2], rowco);
    att_split<<<64 * SPLIT, 256, 0, stream>>>(bits, rowco, f1f2_l[2], Whbt, part, kchunk);
    att_reduce<<<1024, 256, 0, stream>>>(part, out, h0, SPLIT);
}